// Round 6
// baseline (294.330 us; speedup 1.0000x reference)
//
#include <hip/hip_runtime.h>

#define N      4096
#define NIN    64
#define NHID   32
#define NOUT   64
#define NHEADS 8
#define H_SP   6
#define D_INT  32
#define MAXDEG 128
#define NPB    4      // nodes per block in K1
#define ROWS   8      // rows per block in K2 (fused)
#define NBLK2  (N / ROWS)     // 512 blocks -> exactly 2/CU, all co-resident
#define WPAD   (MAXDEG + 4)   // +16B so the 8 head-rows hit distinct banks
#define ALPHA  0.2f

// popc(mask & lanemask_lt) — prefix population count for wave64 ballots
__device__ __forceinline__ int mbcnt64(unsigned long long m) {
    return __builtin_amdgcn_mbcnt_hi((unsigned)(m >> 32),
           __builtin_amdgcn_mbcnt_lo((unsigned)m, 0u));
}

// ---------------------------------------------------------------------------
// K1 (fused proj + csr), 4 nodes per block, 1024 blocks. (unchanged except:
// block 0 zeroes the global barrier counter for the fused kernel)
// ---------------------------------------------------------------------------
__global__ __launch_bounds__(256) void k_fused1(
    const float* __restrict__ x, const float* __restrict__ ie,
    const float4* __restrict__ adj4,
    const float* __restrict__ Wsp, const float* __restrict__ asp,
    const float* __restrict__ Wint, const float* __restrict__ aint,
    float* __restrict__ Wh_t, float* __restrict__ src, float* __restrict__ dst_t,
    int* __restrict__ col, int* __restrict__ deg, int* bar)
{
    const int nb   = blockIdx.x * NPB;
    const int tid  = threadIdx.x;
    const int wv   = tid >> 6, lane = tid & 63;
    const int h    = tid >> 5, f    = tid & 31;

    if (blockIdx.x == 0 && tid == 0) *bar = 0;   // reset fused-kernel barrier

    __shared__ float xs_t[NIN][NPB];     // transposed x tile: [col][node]
    __shared__ float ies[NPB][D_INT];

    xs_t[tid & 63][tid >> 6] = x[nb * NIN + tid];
    if (tid < NPB * D_INT) ies[tid >> 5][tid & 31] = ie[nb * D_INT + tid];
    __syncthreads();

    const float* W = (h < H_SP) ? (Wsp + h * NIN * NHID)
                                : (Wint + (h - H_SP) * NIN * NHID);
    float acc[NPB] = {0.f, 0.f, 0.f, 0.f};
#pragma unroll
    for (int c = 0; c < NIN; ++c) {
        const float wval = W[c * NHID + f];
        const float4 xv  = *(const float4*)&xs_t[c][0];   // broadcast b128
        acc[0] += xv.x * wval; acc[1] += xv.y * wval;
        acc[2] += xv.z * wval; acc[3] += xv.w * wval;
    }
#pragma unroll
    for (int m = 0; m < NPB; ++m)
        Wh_t[(size_t)(nb + m) * 256 + tid] = acc[m];   // coalesced 1 KB stores

    const float a1v = (h < H_SP) ? asp[h * 64 + f]      : aint[(h - H_SP) * 64 + f];
    const float a2v = (h < H_SP) ? asp[h * 64 + 32 + f] : aint[(h - H_SP) * 64 + 32 + f];
#pragma unroll
    for (int m = 0; m < NPB; ++m) {
        const float b = (h < H_SP) ? acc[m] : ies[m][f];
        float s1 = b * a1v, s2 = b * a2v;
#pragma unroll
        for (int mm = 16; mm >= 1; mm >>= 1) {
            s1 += __shfl_xor(s1, mm);
            s2 += __shfl_xor(s2, mm);
        }
        if (f == 0) { src[h * N + nb + m] = s1; dst_t[(nb + m) * 8 + h] = s2; }
    }

    // --- csr: wave wv compacts row nb+wv via ballots ---
    const int r = nb + wv;
    const float4* row = adj4 + (size_t)r * (N / 4);
    int cnt = 0;
#pragma unroll 4
    for (int t = 0; t < 16; ++t) {
        float4 v = row[t * 64 + lane];
        unsigned long long bx = __ballot(v.x > 0.f);
        unsigned long long by = __ballot(v.y > 0.f);
        unsigned long long bz = __ballot(v.z > 0.f);
        unsigned long long bw = __ballot(v.w > 0.f);
        const int tx = __popcll(bx), ty = __popcll(by);
        const int tz = __popcll(bz), tw = __popcll(bw);
        const int idx0 = (t * 64 + lane) * 4;
        const int px = cnt + mbcnt64(bx);
        const int py = cnt + tx + mbcnt64(by);
        const int pz = cnt + tx + ty + mbcnt64(bz);
        const int pw = cnt + tx + ty + tz + mbcnt64(bw);
        if (v.x > 0.f && px < MAXDEG) col[r * MAXDEG + px] = idx0;
        if (v.y > 0.f && py < MAXDEG) col[r * MAXDEG + py] = idx0 + 1;
        if (v.z > 0.f && pz < MAXDEG) col[r * MAXDEG + pz] = idx0 + 2;
        if (v.w > 0.f && pw < MAXDEG) col[r * MAXDEG + pw] = idx0 + 3;
        cnt += tx + ty + tz + tw;
    }
    if (lane == 0) deg[r] = (cnt < MAXDEG) ? cnt : MAXDEG;
}

// ---------------------------------------------------------------------------
// K2+K3 FUSED: 8 rows per 512-thread block, 512 blocks (=2/CU, ALL blocks
// co-resident -> device-scope spin barrier is deadlock-free).
//  phases 1-4: identical math to round-5 K2 (shuffle-free softmax, dwordx4
//    gather with riding denominator, block-shared Wout, o2 store; o1 kept
//    in-register -- no global round trip).
//  barrier: threadfence -> syncthreads -> tid0 fetch_add(release)+spin
//    acquire until 512 -> syncthreads -> threadfence.
//  phase 5 (old K3): wave wv re-serves row r; cs[] still in LDS, d & o1[r]
//    in registers -> no col/deg/o1 reloads. Same sub-group gather as R5.
// ---------------------------------------------------------------------------
__global__ __launch_bounds__(512, 4) void k_attn1who23(
    const int* __restrict__ col, const int* __restrict__ deg,
    const float* __restrict__ Wh_t, const float* __restrict__ src,
    const float* __restrict__ dst_t, const float* __restrict__ Wout,
    const float* __restrict__ aout,
    float* __restrict__ Who, float* __restrict__ o2,
    float* __restrict__ out, int* bar)
{
    const int r0   = blockIdx.x * ROWS;
    const int tid  = threadIdx.x;
    const int wv   = tid >> 6, lane = tid & 63;
    const int r    = r0 + wv;                    // wave wv owns row r

    __shared__ __align__(16) int   cs[ROWS][MAXDEG];            // 4 KB
    __shared__ __align__(16) float w_t[ROWS][NHEADS][WPAD];     // 33 KB
    __shared__ __align__(16) float hs[ROWS][NHEADS * NHID];     // 8 KB

    // ---- phase 1 (wave-local, shuffle-free): raw exp weights for row r ----
    const int d  = deg[r];
    const int j0 = (lane < d)      ? col[r * MAXDEG + lane]      : 0;
    const int j1 = (lane + 64 < d) ? col[r * MAXDEG + 64 + lane] : 0;
    cs[wv][lane]      = j0;
    cs[wv][lane + 64] = j1;

    float sr[NHEADS];
#pragma unroll
    for (int h = 0; h < NHEADS; ++h) sr[h] = src[h * N + r];   // wave-uniform

    float dA[NHEADS] = {}, dB[NHEADS] = {};
    if (lane < d) {
        *(float4*)&dA[0] = *(const float4*)&dst_t[j0 * 8];
        *(float4*)&dA[4] = *(const float4*)&dst_t[j0 * 8 + 4];
    }
    if (lane + 64 < d) {
        *(float4*)&dB[0] = *(const float4*)&dst_t[j1 * 8];
        *(float4*)&dB[4] = *(const float4*)&dst_t[j1 * 8 + 4];
    }

#pragma unroll
    for (int h = 0; h < NHEADS; ++h) {
        float a = sr[h] + dA[h]; a = a > 0.f ? a : ALPHA * a;
        float b = sr[h] + dB[h]; b = b > 0.f ? b : ALPHA * b;
        w_t[wv][h][lane]      = (lane < d)      ? __expf(a) : 0.f;
        w_t[wv][h][lane + 64] = (lane + 64 < d) ? __expf(b) : 0.f;
    }

    // ---- phase 2 (wave-local): gather row r; denominator rides along ----
    const float* wrow = &w_t[wv][lane >> 3][0];
    const int*   csr_ = &cs[wv][0];
    float4 acc = make_float4(0.f, 0.f, 0.f, 0.f);
    float  ws  = 0.f;                                    // head denominator
    const int d4 = (d + 3) & ~3;
    for (int k = 0; k < d4; k += 4) {
        const int4   jj = *(const int4*)&csr_[k];        // uniform broadcast
        const float4 wq = *(const float4*)&wrow[k];      // 4 neighbor weights
        const float4 ga = *(const float4*)&Wh_t[(size_t)jj.x * 256 + 4 * lane];
        const float4 gb = *(const float4*)&Wh_t[(size_t)jj.y * 256 + 4 * lane];
        const float4 gc = *(const float4*)&Wh_t[(size_t)jj.z * 256 + 4 * lane];
        const float4 gd = *(const float4*)&Wh_t[(size_t)jj.w * 256 + 4 * lane];
        ws    += (wq.x + wq.y) + (wq.z + wq.w);
        acc.x += wq.x * ga.x + wq.y * gb.x + wq.z * gc.x + wq.w * gd.x;
        acc.y += wq.x * ga.y + wq.y * gb.y + wq.z * gc.y + wq.w * gd.y;
        acc.z += wq.x * ga.z + wq.y * gb.z + wq.z * gc.z + wq.w * gd.z;
        acc.w += wq.x * ga.w + wq.y * gb.w + wq.z * gc.w + wq.w * gd.w;
    }
    const float winv = 1.f / ws;
    acc.x *= winv; acc.y *= winv; acc.z *= winv; acc.w *= winv;
    acc.x = acc.x > 0.f ? acc.x : __expf(acc.x) - 1.f;   // elu (concat heads)
    acc.y = acc.y > 0.f ? acc.y : __expf(acc.y) - 1.f;
    acc.z = acc.z > 0.f ? acc.z : __expf(acc.z) - 1.f;
    acc.w = acc.w > 0.f ? acc.w : __expf(acc.w) - 1.f;
    *(float4*)&hs[wv][4 * lane] = acc;                   // hs[wv][e] = elem e
    __syncthreads();    // hs cross-wave; all w_t reads done (overlay next)

    // ---- phase 3: Who = h @ Wout; wave wv owns c-slice [wv*32, wv*32+32) ----
    float* part = &w_t[0][0][0];              // [8 waves][8 rows][64] overlay
    {
        float wreg[32];
#pragma unroll
        for (int cc = 0; cc < 32; ++cc)
            wreg[cc] = Wout[(wv * 32 + cc) * NOUT + lane];
#pragma unroll
        for (int m = 0; m < ROWS; ++m) {
            float a = 0.f;
#pragma unroll
            for (int cc = 0; cc < 32; cc += 4) {
                const float4 hv = *(const float4*)&hs[m][wv * 32 + cc];  // uniform
                a += hv.x * wreg[cc]     + hv.y * wreg[cc + 1]
                   + hv.z * wreg[cc + 2] + hv.w * wreg[cc + 3];
            }
            part[(wv * ROWS + m) * NOUT + lane] = a;
        }
    }
    __syncthreads();

    // ---- phase 4: wave wv finalizes row r; o1 stays in-register ----
    float who = 0.f;
#pragma unroll
    for (int q8 = 0; q8 < 8; ++q8) who += part[(q8 * ROWS + wv) * NOUT + lane];
    Who[(size_t)r * NOUT + lane] = who;
    float v1 = who * aout[lane];
    float v2 = who * aout[NOUT + lane];
#pragma unroll
    for (int m = 32; m >= 1; m >>= 1) {
        v1 += __shfl_xor(v1, m);               // after butterfly: ALL lanes
        v2 += __shfl_xor(v2, m);
    }
    if (lane == 0) o2[r] = v2;

    // ---- resident-grid barrier: Who/o2 of ALL blocks become visible ----
    __threadfence();                            // release own stores
    __syncthreads();                            // whole block done storing
    if (tid == 0) {
        __hip_atomic_fetch_add(bar, 1, __ATOMIC_RELEASE, __HIP_MEMORY_SCOPE_AGENT);
        int guard = 0;
        while (__hip_atomic_load(bar, __ATOMIC_ACQUIRE, __HIP_MEMORY_SCOPE_AGENT)
                   < NBLK2 && ++guard < (1 << 30)) {}
    }
    __syncthreads();
    __threadfence();                            // acquire others' stores

    // ---- phase 5 (old K3): wave wv serves row r; cs/d/o1 already local ----
    const float sro = v1;                       // o1[r], wave-uniform
    float p0 = 0.f, p1 = 0.f;                   // raw exp weights, 0 padded
    if (lane < d) {
        float e = sro + o2[j0]; e = e > 0.f ? e : ALPHA * e;
        p0 = __expf(e);
    }
    if (lane + 64 < d) {
        float e = sro + o2[j1]; e = e > 0.f ? e : ALPHA * e;
        p1 = __expf(e);
    }

    const int sub = lane >> 4, q = lane & 15;
    float4 oac = make_float4(0.f, 0.f, 0.f, 0.f);
    float  sw  = 0.f;                           // denominator partial
    const int dlo = d < 64 ? d : 64;
    const int d4a = (dlo + 3) & ~3;
#pragma unroll 2
    for (int k = 0; k < d4a; k += 4) {
        const int   jj = __shfl(j0, k + sub);
        const float ww = __shfl(p0, k + sub);
        const float4 g = *(const float4*)&Who[(size_t)jj * NOUT + 4 * q];
        sw    += ww;
        oac.x += ww * g.x; oac.y += ww * g.y;
        oac.z += ww * g.z; oac.w += ww * g.w;
    }
    const int d4b = (d + 3) & ~3;
    for (int k = 64; k < d4b; k += 4) {
        const int   jj = __shfl(j1, (k - 64) + sub);
        const float ww = __shfl(p1, (k - 64) + sub);
        const float4 g = *(const float4*)&Who[(size_t)jj * NOUT + 4 * q];
        sw    += ww;
        oac.x += ww * g.x; oac.y += ww * g.y;
        oac.z += ww * g.z; oac.w += ww * g.w;
    }
    // fold the 4 sub-group partials (lanes xor 16, 32); sw rides along
#pragma unroll
    for (int m = 16; m <= 32; m <<= 1) {
        oac.x += __shfl_xor(oac.x, m);
        oac.y += __shfl_xor(oac.y, m);
        oac.z += __shfl_xor(oac.z, m);
        oac.w += __shfl_xor(oac.w, m);
        sw    += __shfl_xor(sw,    m);
    }
    if (lane < 16) {
        const float inv = 1.f / sw;
        float4 o;
        o.x = tanhf(oac.x * inv); o.y = tanhf(oac.y * inv);
        o.z = tanhf(oac.z * inv); o.w = tanhf(oac.w * inv);
        *(float4*)&out[(size_t)r * NOUT + 4 * lane] = o;
    }
}

// ---------------------------------------------------------------------------
extern "C" void kernel_launch(void* const* d_in, const int* in_sizes, int n_in,
                              void* d_out, int out_size, void* d_ws, size_t ws_size,
                              hipStream_t stream) {
    const float* x    = (const float*)d_in[0];   // [4096,64]
    const float* adj  = (const float*)d_in[1];   // [4096,4096]
    const float* ie   = (const float*)d_in[2];   // [4096,32]
    const float* Wsp  = (const float*)d_in[3];   // [6,64,32]
    const float* asp  = (const float*)d_in[4];   // [6,64]
    const float* Wint = (const float*)d_in[5];   // [2,64,32]
    const float* aint = (const float*)d_in[6];   // [2,64]
    const float* Wout = (const float*)d_in[7];   // [256,64]
    const float* aout = (const float*)d_in[8];   // [128]
    float* out = (float*)d_out;                  // [4096,64]

    float* ws    = (float*)d_ws;
    float* Wh_t  = ws;                    // [4096][256]  node-major
    float* src   = Wh_t + 1048576;        // [8][4096]
    float* dst_t = src  + 32768;          // [4096][8]
    float* Who   = dst_t + 32768;         // [4096][64]
    float* o1    = Who  + 262144;         // [4096] (unused; layout kept)
    float* o2    = o1   + 4096;           // [4096]
    int*   col   = (int*)(o2 + 4096);     // [4096][128]
    int*   deg   = col + 4096 * MAXDEG;   // [4096]
    int*   bar   = deg + 4096;            // [1] global barrier counter

    k_fused1    <<<N / NPB, 256, 0, stream>>>(x, ie, (const float4*)adj, Wsp, asp,
                                              Wint, aint, Wh_t, src, dst_t, col,
                                              deg, bar);
    k_attn1who23<<<NBLK2,   512, 0, stream>>>(col, deg, Wh_t, src, dst_t, Wout,
                                              aout, Who, o2, out, bar);
}

// Round 7
// 140.981 us; speedup vs baseline: 2.0877x; 2.0877x over previous
//
#include <hip/hip_runtime.h>
#include <hip/hip_fp16.h>

#define N      4096
#define NIN    64
#define NHID   32
#define NOUT   64
#define NHEADS 8
#define H_SP   6
#define D_INT  32
#define MAXDEG 128
#define NPB    4      // nodes per block in K1
#define ROWS   8      // rows per block in K2
#define WPAD   (MAXDEG + 4)   // +16B so the 8 head-rows hit distinct banks
#define ALPHA  0.2f

// popc(mask & lanemask_lt) — prefix population count for wave64 ballots
__device__ __forceinline__ int mbcnt64(unsigned long long m) {
    return __builtin_amdgcn_mbcnt_hi((unsigned)(m >> 32),
           __builtin_amdgcn_mbcnt_lo((unsigned)m, 0u));
}

// ---------------------------------------------------------------------------
// K1 (fused proj + csr), 4 nodes per block, 1024 blocks. Same as round 5
// except Wh is stored fp16 (2 MB total -> fits every XCD L2; halves K2's
// gather traffic). Stores stay coalesced (64 lanes x 2 B = 128 B/instr).
// ---------------------------------------------------------------------------
__global__ __launch_bounds__(256) void k_fused1(
    const float* __restrict__ x, const float* __restrict__ ie,
    const float4* __restrict__ adj4,
    const float* __restrict__ Wsp, const float* __restrict__ asp,
    const float* __restrict__ Wint, const float* __restrict__ aint,
    __half* __restrict__ Wh_h, float* __restrict__ src, float* __restrict__ dst_t,
    int* __restrict__ col, int* __restrict__ deg)
{
    const int nb   = blockIdx.x * NPB;
    const int tid  = threadIdx.x;
    const int wv   = tid >> 6, lane = tid & 63;
    const int h    = tid >> 5, f    = tid & 31;

    __shared__ float xs_t[NIN][NPB];     // transposed x tile: [col][node]
    __shared__ float ies[NPB][D_INT];

    xs_t[tid & 63][tid >> 6] = x[nb * NIN + tid];
    if (tid < NPB * D_INT) ies[tid >> 5][tid & 31] = ie[nb * D_INT + tid];
    __syncthreads();

    const float* W = (h < H_SP) ? (Wsp + h * NIN * NHID)
                                : (Wint + (h - H_SP) * NIN * NHID);
    float acc[NPB] = {0.f, 0.f, 0.f, 0.f};
#pragma unroll
    for (int c = 0; c < NIN; ++c) {
        const float wval = W[c * NHID + f];
        const float4 xv  = *(const float4*)&xs_t[c][0];   // broadcast b128
        acc[0] += xv.x * wval; acc[1] += xv.y * wval;
        acc[2] += xv.z * wval; acc[3] += xv.w * wval;
    }
#pragma unroll
    for (int m = 0; m < NPB; ++m)
        Wh_h[(size_t)(nb + m) * 256 + tid] = __float2half(acc[m]);

    const float a1v = (h < H_SP) ? asp[h * 64 + f]      : aint[(h - H_SP) * 64 + f];
    const float a2v = (h < H_SP) ? asp[h * 64 + 32 + f] : aint[(h - H_SP) * 64 + 32 + f];
#pragma unroll
    for (int m = 0; m < NPB; ++m) {
        const float b = (h < H_SP) ? acc[m] : ies[m][f];
        float s1 = b * a1v, s2 = b * a2v;
#pragma unroll
        for (int mm = 16; mm >= 1; mm >>= 1) {
            s1 += __shfl_xor(s1, mm);
            s2 += __shfl_xor(s2, mm);
        }
        if (f == 0) { src[h * N + nb + m] = s1; dst_t[(nb + m) * 8 + h] = s2; }
    }

    // --- csr: wave wv compacts row nb+wv via ballots ---
    const int r = nb + wv;
    const float4* row = adj4 + (size_t)r * (N / 4);
    int cnt = 0;
#pragma unroll 4
    for (int t = 0; t < 16; ++t) {
        float4 v = row[t * 64 + lane];
        unsigned long long bx = __ballot(v.x > 0.f);
        unsigned long long by = __ballot(v.y > 0.f);
        unsigned long long bz = __ballot(v.z > 0.f);
        unsigned long long bw = __ballot(v.w > 0.f);
        const int tx = __popcll(bx), ty = __popcll(by);
        const int tz = __popcll(bz), tw = __popcll(bw);
        const int idx0 = (t * 64 + lane) * 4;
        const int px = cnt + mbcnt64(bx);
        const int py = cnt + tx + mbcnt64(by);
        const int pz = cnt + tx + ty + mbcnt64(bz);
        const int pw = cnt + tx + ty + tz + mbcnt64(bw);
        if (v.x > 0.f && px < MAXDEG) col[r * MAXDEG + px] = idx0;
        if (v.y > 0.f && py < MAXDEG) col[r * MAXDEG + py] = idx0 + 1;
        if (v.z > 0.f && pz < MAXDEG) col[r * MAXDEG + pz] = idx0 + 2;
        if (v.w > 0.f && pw < MAXDEG) col[r * MAXDEG + pw] = idx0 + 3;
        cnt += tx + ty + tz + tw;
    }
    if (lane == 0) deg[r] = (cnt < MAXDEG) ? cnt : MAXDEG;
}

// ---------------------------------------------------------------------------
// K2 (fused attn1 + Who): 8 rows per 512-thread block, 512 blocks.
// Round-5 structure (shuffle-free softmax; riding denominator; block-shared
// Wout) with the gather reading fp16 Wh: 8 B/lane dwordx2 per neighbor row
// (86 MB total, XCD-L2-resident) -> gather phase ~2x faster.
// ---------------------------------------------------------------------------
__global__ __launch_bounds__(512, 4) void k_attn1who(
    const int* __restrict__ col, const int* __restrict__ deg,
    const __half* __restrict__ Wh_h, const float* __restrict__ src,
    const float* __restrict__ dst_t, const float* __restrict__ Wout,
    const float* __restrict__ aout,
    float* __restrict__ Who, float* __restrict__ o1, float* __restrict__ o2)
{
    const int r0   = blockIdx.x * ROWS;
    const int tid  = threadIdx.x;
    const int wv   = tid >> 6, lane = tid & 63;
    const int r    = r0 + wv;                    // wave wv owns row r

    __shared__ __align__(16) int   cs[ROWS][MAXDEG];            // 4 KB
    __shared__ __align__(16) float w_t[ROWS][NHEADS][WPAD];     // 33 KB
    __shared__ __align__(16) float hs[ROWS][NHEADS * NHID];     // 8 KB

    // ---- phase 1 (wave-local, shuffle-free): raw exp weights for row r ----
    const int d  = deg[r];
    const int j0 = (lane < d)      ? col[r * MAXDEG + lane]      : 0;
    const int j1 = (lane + 64 < d) ? col[r * MAXDEG + 64 + lane] : 0;
    cs[wv][lane]      = j0;
    cs[wv][lane + 64] = j1;

    float sr[NHEADS];
#pragma unroll
    for (int h = 0; h < NHEADS; ++h) sr[h] = src[h * N + r];   // wave-uniform

    float dA[NHEADS] = {}, dB[NHEADS] = {};
    if (lane < d) {
        *(float4*)&dA[0] = *(const float4*)&dst_t[j0 * 8];
        *(float4*)&dA[4] = *(const float4*)&dst_t[j0 * 8 + 4];
    }
    if (lane + 64 < d) {
        *(float4*)&dB[0] = *(const float4*)&dst_t[j1 * 8];
        *(float4*)&dB[4] = *(const float4*)&dst_t[j1 * 8 + 4];
    }

#pragma unroll
    for (int h = 0; h < NHEADS; ++h) {
        float a = sr[h] + dA[h]; a = a > 0.f ? a : ALPHA * a;
        float b = sr[h] + dB[h]; b = b > 0.f ? b : ALPHA * b;
        w_t[wv][h][lane]      = (lane < d)      ? __expf(a) : 0.f;
        w_t[wv][h][lane + 64] = (lane + 64 < d) ? __expf(b) : 0.f;
    }

    // ---- phase 2 (wave-local): fp16 gather; denominator rides along ----
    // lane covers elements 4*lane..4*lane+3 (half2 slots 2*lane, 2*lane+1),
    // all in head (lane>>3).
    const float* wrow = &w_t[wv][lane >> 3][0];
    const int*   csr_ = &cs[wv][0];
    const __half2* base = (const __half2*)Wh_h;   // 128 half2 per node row
    float4 acc = make_float4(0.f, 0.f, 0.f, 0.f);
    float  ws  = 0.f;                                    // head denominator
    const int d4 = (d + 3) & ~3;
    for (int k = 0; k < d4; k += 4) {
        const int4   jj = *(const int4*)&csr_[k];        // uniform broadcast
        const float4 wq = *(const float4*)&wrow[k];      // 4 neighbor weights
        const __half2* pa = base + (size_t)jj.x * 128 + 2 * lane;
        const __half2* pb = base + (size_t)jj.y * 128 + 2 * lane;
        const __half2* pc = base + (size_t)jj.z * 128 + 2 * lane;
        const __half2* pd = base + (size_t)jj.w * 128 + 2 * lane;
        const float2 a0 = __half22float2(pa[0]), a1 = __half22float2(pa[1]);
        const float2 b0 = __half22float2(pb[0]), b1 = __half22float2(pb[1]);
        const float2 c0 = __half22float2(pc[0]), c1 = __half22float2(pc[1]);
        const float2 e0 = __half22float2(pd[0]), e1 = __half22float2(pd[1]);
        ws    += (wq.x + wq.y) + (wq.z + wq.w);
        acc.x += wq.x * a0.x + wq.y * b0.x + wq.z * c0.x + wq.w * e0.x;
        acc.y += wq.x * a0.y + wq.y * b0.y + wq.z * c0.y + wq.w * e0.y;
        acc.z += wq.x * a1.x + wq.y * b1.x + wq.z * c1.x + wq.w * e1.x;
        acc.w += wq.x * a1.y + wq.y * b1.y + wq.z * c1.y + wq.w * e1.y;
    }
    const float winv = 1.f / ws;
    acc.x *= winv; acc.y *= winv; acc.z *= winv; acc.w *= winv;
    acc.x = acc.x > 0.f ? acc.x : __expf(acc.x) - 1.f;   // elu (concat heads)
    acc.y = acc.y > 0.f ? acc.y : __expf(acc.y) - 1.f;
    acc.z = acc.z > 0.f ? acc.z : __expf(acc.z) - 1.f;
    acc.w = acc.w > 0.f ? acc.w : __expf(acc.w) - 1.f;
    *(float4*)&hs[wv][4 * lane] = acc;                   // hs[wv][e] = elem e
    __syncthreads();    // hs cross-wave; all w_t reads done (overlay next)

    // ---- phase 3: Who = h @ Wout; wave wv owns c-slice [wv*32, wv*32+32) ----
    float* part = &w_t[0][0][0];              // [8 waves][8 rows][64] overlay
    {
        float wreg[32];
#pragma unroll
        for (int cc = 0; cc < 32; ++cc)
            wreg[cc] = Wout[(wv * 32 + cc) * NOUT + lane];
#pragma unroll
        for (int m = 0; m < ROWS; ++m) {
            float a = 0.f;
#pragma unroll
            for (int cc = 0; cc < 32; cc += 4) {
                const float4 hv = *(const float4*)&hs[m][wv * 32 + cc];  // uniform
                a += hv.x * wreg[cc]     + hv.y * wreg[cc + 1]
                   + hv.z * wreg[cc + 2] + hv.w * wreg[cc + 3];
            }
            part[(wv * ROWS + m) * NOUT + lane] = a;
        }
    }
    __syncthreads();

    // ---- phase 4: wave wv finalizes row r ----
    float who = 0.f;
#pragma unroll
    for (int q8 = 0; q8 < 8; ++q8) who += part[(q8 * ROWS + wv) * NOUT + lane];
    Who[(size_t)r * NOUT + lane] = who;
    float v1 = who * aout[lane];
    float v2 = who * aout[NOUT + lane];
#pragma unroll
    for (int m = 32; m >= 1; m >>= 1) {
        v1 += __shfl_xor(v1, m);
        v2 += __shfl_xor(v2, m);
    }
    if (lane == 0) { o1[r] = v1; o2[r] = v2; }
}

// ---------------------------------------------------------------------------
// K3 (attn2): wave-per-row, sync-free, no LDS. Shuffle-free softmax; sub-group
// fp32 gather of Who (unchanged from round 5).
// ---------------------------------------------------------------------------
__global__ __launch_bounds__(256) void k_attn2(
    const int* __restrict__ col, const int* __restrict__ deg,
    const float* __restrict__ Who, const float* __restrict__ o1,
    const float* __restrict__ o2, float* __restrict__ out)
{
    const int tid  = threadIdx.x;
    const int wv   = tid >> 6, lane = tid & 63;
    const int r    = blockIdx.x * 4 + wv;

    const int d  = deg[r];
    const int j0 = (lane < d)      ? col[r * MAXDEG + lane]      : 0;
    const int j1 = (lane + 64 < d) ? col[r * MAXDEG + 64 + lane] : 0;
    const float sr = o1[r];

    float p0 = 0.f, p1 = 0.f;                     // raw exp weights, 0 padded
    if (lane < d) {
        float e = sr + o2[j0]; e = e > 0.f ? e : ALPHA * e;
        p0 = __expf(e);
    }
    if (lane + 64 < d) {
        float e = sr + o2[j1]; e = e > 0.f ? e : ALPHA * e;
        p1 = __expf(e);
    }

    const int sub = lane >> 4, q = lane & 15;
    float4 acc = make_float4(0.f, 0.f, 0.f, 0.f);
    float  sw  = 0.f;                             // denominator partial
    const int dlo  = d < 64 ? d : 64;
    const int d4a  = (dlo + 3) & ~3;
#pragma unroll 2
    for (int k = 0; k < d4a; k += 4) {
        const int   jj = __shfl(j0, k + sub);
        const float ww = __shfl(p0, k + sub);
        const float4 g = *(const float4*)&Who[(size_t)jj * NOUT + 4 * q];
        sw    += ww;
        acc.x += ww * g.x; acc.y += ww * g.y;
        acc.z += ww * g.z; acc.w += ww * g.w;
    }
    const int d4b = (d + 3) & ~3;
    for (int k = 64; k < d4b; k += 4) {
        const int   jj = __shfl(j1, (k - 64) + sub);
        const float ww = __shfl(p1, (k - 64) + sub);
        const float4 g = *(const float4*)&Who[(size_t)jj * NOUT + 4 * q];
        sw    += ww;
        acc.x += ww * g.x; acc.y += ww * g.y;
        acc.z += ww * g.z; acc.w += ww * g.w;
    }
    // fold the 4 sub-group partials (lanes xor 16, 32); sw rides along
#pragma unroll
    for (int m = 16; m <= 32; m <<= 1) {
        acc.x += __shfl_xor(acc.x, m);
        acc.y += __shfl_xor(acc.y, m);
        acc.z += __shfl_xor(acc.z, m);
        acc.w += __shfl_xor(acc.w, m);
        sw    += __shfl_xor(sw,    m);
    }
    if (lane < 16) {
        const float inv = 1.f / sw;
        float4 o;
        o.x = tanhf(acc.x * inv); o.y = tanhf(acc.y * inv);
        o.z = tanhf(acc.z * inv); o.w = tanhf(acc.w * inv);
        *(float4*)&out[(size_t)r * NOUT + 4 * lane] = o;
    }
}

// ---------------------------------------------------------------------------
extern "C" void kernel_launch(void* const* d_in, const int* in_sizes, int n_in,
                              void* d_out, int out_size, void* d_ws, size_t ws_size,
                              hipStream_t stream) {
    const float* x    = (const float*)d_in[0];   // [4096,64]
    const float* adj  = (const float*)d_in[1];   // [4096,4096]
    const float* ie   = (const float*)d_in[2];   // [4096,32]
    const float* Wsp  = (const float*)d_in[3];   // [6,64,32]
    const float* asp  = (const float*)d_in[4];   // [6,64]
    const float* Wint = (const float*)d_in[5];   // [2,64,32]
    const float* aint = (const float*)d_in[6];   // [2,64]
    const float* Wout = (const float*)d_in[7];   // [256,64]
    const float* aout = (const float*)d_in[8];   // [128]
    float* out = (float*)d_out;                  // [4096,64]

    float* ws    = (float*)d_ws;
    __half* Wh_h = (__half*)ws;           // [4096][256] fp16 (2 MB)
    float* src   = ws + 524288;           // [8][4096]
    float* dst_t = src  + 32768;          // [4096][8]
    float* Who   = dst_t + 32768;         // [4096][64]
    float* o1    = Who  + 262144;         // [4096]
    float* o2    = o1   + 4096;           // [4096]
    int*   col   = (int*)(o2 + 4096);     // [4096][128]
    int*   deg   = col + 4096 * MAXDEG;   // [4096]

    k_fused1  <<<N / NPB,  256, 0, stream>>>(x, ie, (const float4*)adj, Wsp, asp,
                                             Wint, aint, Wh_h, src, dst_t, col, deg);
    k_attn1who<<<N / ROWS, 512, 0, stream>>>(col, deg, Wh_h, src, dst_t, Wout, aout,
                                             Who, o1, o2);
    k_attn2   <<<N / 4,    256, 0, stream>>>(col, deg, Who, o1, o2, out);
}